// Round 1
// baseline (313.113 us; speedup 1.0000x reference)
//
#include <hip/hip_runtime.h>
#include <hip/hip_fp16.h>
#include <math.h>

#define N_NODES 50000
#define N_EDGES 800000
#define N_GRAPHS 1024
#define DIM 64
#define PAD 64           // padded CSR slots per destination (max in-degree ~45)
#define ZROW N_NODES     // index of the guaranteed-zero row in t'
#define SLICE 6250       // N_NODES / 8 destinations per XCD slice
#define QBLK 208         // blocks per slice

// t' is stored as TWO 32-dim planes of fp16 (3.2 MB each) so one gather
// pass's random working set fits in a single XCD's 4 MiB L2.
// plane p holds dims [32p, 32p+32); row n of plane p = th + p*PLANE + n*32.
#define PLANE ((size_t)(N_NODES + 1) * 32)   // halves per plane (incl. zero row)

typedef int   v4i __attribute__((ext_vector_type(4)));
typedef float v2f __attribute__((ext_vector_type(2)));
typedef float v4f __attribute__((ext_vector_type(4)));

// non-temporal helpers: keep streaming traffic from evicting the hot t' plane
__device__ __forceinline__ int4 ntld4i(const int* p) {
    v4i v = __builtin_nontemporal_load((const v4i*)p);
    return make_int4(v[0], v[1], v[2], v[3]);
}
__device__ __forceinline__ float4 ntld4f(const float* p) {
    v4f v = __builtin_nontemporal_load((const v4f*)p);
    return make_float4(v[0], v[1], v[2], v[3]);
}
__device__ __forceinline__ void ntst2f(float2* p, float x, float y) {
    v2f v; v[0] = x; v[1] = y;
    __builtin_nontemporal_store(v, (v2f*)p);
}

// ---------------- one-pass padded-CSR build, XCD-sliced ----------------

__global__ void deg_fill(const int* __restrict__ row, const int* __restrict__ col,
                         int* __restrict__ ideg, int* __restrict__ esrc_pad) {
    int slice = blockIdx.x & 7;
    int q = blockIdx.x >> 3;          // 0..QBLK-1
    int lo = slice * SLICE, hi = lo + SLICE;
    for (int e = q * 256 + threadIdx.x; e < N_EDGES; e += QBLK * 256) {
        int c = __builtin_nontemporal_load(col + e);
        if (c >= lo && c < hi) {
            int rank = atomicAdd(&ideg[c], 1);
            if (rank < PAD) esrc_pad[c * PAD + rank] = __builtin_nontemporal_load(row + e);
        }
    }
}

// ---------------- dense transforms (t' = dinv * (h @ W), fp16 planes) ----------------

__global__ void gemm9(const float* __restrict__ x, const float* __restrict__ W,
                      const int* __restrict__ ideg, __half* __restrict__ th) {
    __shared__ float Wl[9 * DIM];
    int tid = threadIdx.x;
    for (int i = tid; i < 9 * DIM; i += 256) Wl[i] = W[i];
    __syncthreads();
    int node = blockIdx.x * 4 + (tid >> 6);
    int d = tid & 63;
    if (node >= N_NODES) return;
    const float* xr = x + (size_t)node * 9;
    float acc = 0.0f;
#pragma unroll
    for (int k = 0; k < 9; ++k) acc += xr[k] * Wl[k * DIM + d];
    float dv = rsqrtf((float)ideg[node] + 1.0f);
    th[(size_t)(d >> 5) * PLANE + (size_t)node * 32 + (d & 31)] = __float2half(dv * acc);
}

// layers 1-3: 64x64 register-tile GEMM, 64-node tiles, fp16+dinv planar output.
__global__ void gemm64(const float* __restrict__ h, const float* __restrict__ W,
                       const int* __restrict__ ideg, __half* __restrict__ th) {
    __shared__ float At[64][68];
    __shared__ float Bl[64][68];
    int tid = threadIdx.x;
    int n0 = blockIdx.x * 64;

    {
        const float4* W4 = (const float4*)W;
#pragma unroll
        for (int i = 0; i < 4; ++i) {
            int idx = tid + 256 * i;
            int k = idx >> 4;
            int d4 = idx & 15;
            float4 v = W4[idx];
            *(float4*)&Bl[k][d4 * 4] = v;
        }
    }
    {
        int node = tid >> 2;
        int seg = tid & 3;
        int gn = n0 + node;
        bool ok = gn < N_NODES;
#pragma unroll
        for (int i = 0; i < 4; ++i) {
            int c4 = seg * 4 + i;
            float4 v = ok ? ntld4f(h + (size_t)gn * 64 + c4 * 4)
                          : make_float4(0.f, 0.f, 0.f, 0.f);
            int d = c4 * 4;
            At[d + 0][node] = v.x;
            At[d + 1][node] = v.y;
            At[d + 2][node] = v.z;
            At[d + 3][node] = v.w;
        }
    }
    __syncthreads();

    int ty = tid >> 4;
    int tx = tid & 15;
    float c00 = 0, c01 = 0, c02 = 0, c03 = 0;
    float c10 = 0, c11 = 0, c12 = 0, c13 = 0;
    float c20 = 0, c21 = 0, c22 = 0, c23 = 0;
    float c30 = 0, c31 = 0, c32 = 0, c33 = 0;
#pragma unroll 8
    for (int k = 0; k < 64; ++k) {
        float4 a = *(const float4*)&At[k][ty * 4];
        float4 b = *(const float4*)&Bl[k][tx * 4];
        c00 += a.x * b.x; c01 += a.x * b.y; c02 += a.x * b.z; c03 += a.x * b.w;
        c10 += a.y * b.x; c11 += a.y * b.y; c12 += a.y * b.z; c13 += a.y * b.w;
        c20 += a.z * b.x; c21 += a.z * b.y; c22 += a.z * b.z; c23 += a.z * b.w;
        c30 += a.w * b.x; c31 += a.w * b.y; c32 += a.w * b.z; c33 += a.w * b.w;
    }
    int gn = n0 + ty * 4;
    uint2* tp = (uint2*)(th + (size_t)(tx >> 3) * PLANE);
    int txl = tx & 7;   // uint2 slot within the plane row (dims 4*txl..4*txl+3 of plane)
#define STORE_ROW(r, CA, CB, CC, CD)                                          \
    if (gn + r < N_NODES) {                                                   \
        float dv = rsqrtf((float)ideg[gn + r] + 1.0f);                        \
        __half2 p0 = __floats2half2_rn(dv * CA, dv * CB);                     \
        __half2 p1 = __floats2half2_rn(dv * CC, dv * CD);                     \
        uint2 o;                                                              \
        o.x = *(unsigned*)&p0;                                                \
        o.y = *(unsigned*)&p1;                                                \
        tp[(size_t)(gn + r) * 8 + txl] = o;                                   \
    }
    STORE_ROW(0, c00, c01, c02, c03)
    STORE_ROW(1, c10, c11, c12, c13)
    STORE_ROW(2, c20, c21, c22, c23)
    STORE_ROW(3, c30, c31, c32, c33)
#undef STORE_ROW
}

// ---------------- gather + bias + tanh: group-per-node, 16-deep, per-plane ----------------
// One launch handles ONE 32-dim plane (3.2 MB random working set -> L2-resident
// per XCD). 16 lanes/node, 4B (half2) per lane per edge row = 64B coalesced row.
// out[n][32p..] = tanh( dinv[n] * (t'[n] + sum_e t'[src_e]) + b[32p..] )

__device__ __forceinline__ float2 h2tof2(unsigned u) {
    __half2 h = *reinterpret_cast<const __half2*>(&u);
    return __half22float2(h);
}

__global__ void gather_tanh(const int* __restrict__ esrc_pad, const int* __restrict__ ideg,
                            const unsigned* __restrict__ thp, const float* __restrict__ b,
                            const int pass, float2* __restrict__ hout2) {
    int tid = threadIdx.x;
    int wid = tid >> 6;
    int lane = tid & 63;
    int sub = lane & 15;   // half2 chunk: plane dims [2*sub, 2*sub+2)
    int grp = lane >> 4;   // 0..3 -> node
    int node = blockIdx.x * 16 + wid * 4 + grp;  // grid = N_NODES/16 = 3125 (exact)

    int deg = min(ideg[node], PAD);
    const int* ep = esrc_pad + node * PAD;

    // self-loop + 4 split accumulators for FMA ILP
    float2 acc0 = h2tof2(thp[(size_t)node * 16 + sub]);
    float2 acc1 = make_float2(0.f, 0.f);
    float2 acc2 = make_float2(0.f, 0.f);
    float2 acc3 = make_float2(0.f, 0.f);

    for (int base = 0; base < deg; base += 16) {
        int4 i0 = ntld4i(ep + base + 0);
        int4 i1 = ntld4i(ep + base + 4);
        int4 i2 = ntld4i(ep + base + 8);
        int4 i3 = ntld4i(ep + base + 12);
        int idx[16] = {i0.x, i0.y, i0.z, i0.w, i1.x, i1.y, i1.z, i1.w,
                       i2.x, i2.y, i2.z, i2.w, i3.x, i3.y, i3.z, i3.w};
        // clamp tail slots (poisoned ws!) to the zero row BEFORE address calc
        int rem = deg - base;
        unsigned r[16];
#pragma unroll
        for (int j = 0; j < 16; ++j) {
            int s = (j < rem) ? idx[j] : ZROW;
            r[j] = thp[(size_t)s * 16 + sub];
        }
#pragma unroll
        for (int j = 0; j < 16; ++j) {
            float2 v = h2tof2(r[j]);
            if ((j & 3) == 0)      { acc0.x += v.x; acc0.y += v.y; }
            else if ((j & 3) == 1) { acc1.x += v.x; acc1.y += v.y; }
            else if ((j & 3) == 2) { acc2.x += v.x; acc2.y += v.y; }
            else                   { acc3.x += v.x; acc3.y += v.y; }
        }
    }

    float ax = (acc0.x + acc1.x) + (acc2.x + acc3.x);
    float ay = (acc0.y + acc1.y) + (acc2.y + acc3.y);

    float2 bv = ((const float2*)b)[pass * 16 + sub];
    float dv = rsqrtf((float)deg + 1.0f);
    float rx = tanhf(dv * ax + bv.x);
    float ry = tanhf(dv * ay + bv.y);
    // hA layout is unchanged: [node][64] floats; float2 slot = node*32 + pass*16 + sub
    ntst2f(&hout2[(size_t)node * 32 + pass * 16 + sub], rx, ry);
}

// ---------------- pooling + output ----------------

__device__ __forceinline__ int lower_bound(const int* a, int n, int key) {
    int lo = 0, hi = n;
    while (lo < hi) {
        int mid = (lo + hi) >> 1;
        if (a[mid] < key) lo = mid + 1; else hi = mid;
    }
    return lo;
}

__global__ void pool_out(const float* __restrict__ h, const int* __restrict__ batch,
                         const float* __restrict__ Wout, const float* __restrict__ bout,
                         float* __restrict__ out) {
    __shared__ float smax[4][DIM];
    __shared__ float ssum[4][DIM];
    __shared__ int bounds[2];
    int g = blockIdx.x;
    int tid = threadIdx.x, w = tid >> 6, d = tid & 63;
    if (tid == 0) {
        bounds[0] = lower_bound(batch, N_NODES, g);
        bounds[1] = lower_bound(batch, N_NODES, g + 1);
    }
    __syncthreads();
    int start = bounds[0], end = bounds[1];
    float mx = -INFINITY, sum = 0.0f;
    for (int n = start + w; n < end; n += 4) {
        float v = __builtin_nontemporal_load(h + (size_t)n * DIM + d);
        mx = fmaxf(mx, v);
        sum += v;
    }
    smax[w][d] = mx;
    ssum[w][d] = sum;
    __syncthreads();
    if (w == 0) {
        mx = fmaxf(fmaxf(smax[0][d], smax[1][d]), fmaxf(smax[2][d], smax[3][d]));
        sum = ssum[0][d] + ssum[1][d] + ssum[2][d] + ssum[3][d];
        float cnt = (float)(end - start);
        float mean = sum / fmaxf(cnt, 1.0f);
        float v = mx * Wout[d] + mean * Wout[DIM + d];
#pragma unroll
        for (int off = 32; off > 0; off >>= 1) v += __shfl_down(v, off, 64);
        if (d == 0) out[g] = v + bout[0];
    }
}

// ---------------- launch ----------------

static inline size_t align256(size_t x) { return (x + 255) & ~(size_t)255; }

extern "C" void kernel_launch(void* const* d_in, const int* in_sizes, int n_in,
                              void* d_out, int out_size, void* d_ws, size_t ws_size,
                              hipStream_t stream) {
    const float* x     = (const float*)d_in[0];
    const int*   ei    = (const int*)d_in[1];
    const int*   batch = (const int*)d_in[2];
    const float* W0    = (const float*)d_in[3];
    const float* b0    = (const float*)d_in[4];
    const float* W1    = (const float*)d_in[5];
    const float* b1    = (const float*)d_in[6];
    const float* W2    = (const float*)d_in[7];
    const float* b2    = (const float*)d_in[8];
    const float* W3    = (const float*)d_in[9];
    const float* b3    = (const float*)d_in[10];
    const float* Wout  = (const float*)d_in[11];
    const float* bout  = (const float*)d_in[12];
    float* out = (float*)d_out;

    const int* row = ei;            // source
    const int* col = ei + N_EDGES;  // destination

    char* ws = (char*)d_ws;
    size_t off = 0;
    int*    ideg     = (int*)(ws + off);    off += align256((size_t)N_NODES * 4);
    int*    esrc_pad = (int*)(ws + off);    off += align256((size_t)N_NODES * PAD * 4);
    __half* th       = (__half*)(ws + off); off += align256(2 * PLANE * 2);
    float*  hA       = (float*)(ws + off);  off += align256((size_t)N_NODES * DIM * 4);
    (void)ws_size;

    const int wave_blocks = N_NODES / 4;             // 12500 (gemm9)
    const int gath_blocks = N_NODES / 16;            // 3125  (4 nodes/wave, per plane)
    const int gemm_blocks = (N_NODES + 63) / 64;     // 782

    // one-pass padded-CSR build (XCD-sliced) + zero-row init for both planes
    hipMemsetAsync(ideg, 0, (size_t)N_NODES * 4, stream);
    hipMemsetAsync(th + (size_t)ZROW * 32, 0, 32 * 2, stream);
    hipMemsetAsync(th + PLANE + (size_t)ZROW * 32, 0, 32 * 2, stream);
    deg_fill<<<8 * QBLK, 256, 0, stream>>>(row, col, ideg, esrc_pad);

    // layer 0
    gemm9<<<wave_blocks, 256, 0, stream>>>(x, W0, ideg, th);
    for (int p = 0; p < 2; ++p)
        gather_tanh<<<gath_blocks, 256, 0, stream>>>(
            esrc_pad, ideg, (const unsigned*)(th + (size_t)p * PLANE), b0, p, (float2*)hA);

    // layers 1-3
    const float* Ws[3] = {W1, W2, W3};
    const float* bs[3] = {b1, b2, b3};
    for (int l = 0; l < 3; ++l) {
        gemm64<<<gemm_blocks, 256, 0, stream>>>(hA, Ws[l], ideg, th);
        for (int p = 0; p < 2; ++p)
            gather_tanh<<<gath_blocks, 256, 0, stream>>>(
                esrc_pad, ideg, (const unsigned*)(th + (size_t)p * PLANE), bs[l], p, (float2*)hA);
    }

    // pooling + output
    pool_out<<<N_GRAPHS, 256, 0, stream>>>(hA, batch, Wout, bout, out);
    (void)out_size; (void)n_in; (void)in_sizes;
}